// Round 3
// baseline (606.754 us; speedup 1.0000x reference)
//
#include <hip/hip_runtime.h>
#include <stdint.h>
#include <math.h>

typedef __attribute__((ext_vector_type(8))) short short8;
typedef __attribute__((ext_vector_type(4))) short short4v;
typedef __attribute__((ext_vector_type(4))) float floatx4;

#define DEV static __device__ __forceinline__

DEV float bf2f(unsigned short u){ union { unsigned int i; float f; } c; c.i = ((unsigned int)u) << 16; return c.f; }
DEV unsigned short f2bf(float f){ union { float f; unsigned int i; } c; c.f = f; unsigned int u = c.i; u += 0x7fffu + ((u >> 16) & 1u); return (unsigned short)(u >> 16); }

#if defined(__has_builtin)
#if __has_builtin(__builtin_amdgcn_global_load_lds)
#define USE_GLL 1
#endif
#endif
#ifndef USE_GLL
#define USE_GLL 0
#endif

// async global->LDS, 16B per lane. ldsbase is the wave-uniform base; HW writes base + lane*16.
DEV void gll16(const unsigned short* g, unsigned short* ldsbase, int lane){
#if USE_GLL
  __builtin_amdgcn_global_load_lds((const __attribute__((address_space(1))) void*)g,
                                   (__attribute__((address_space(3))) void*)ldsbase, 16, 0, 0);
#else
  *(short8*)(ldsbase + lane * 8) = *(const short8*)g;
#endif
}

// -------- transpose + convert: out_bf16[C][R] = in_f32[R][C], batched over blockIdx.z ----
__global__ __launch_bounds__(256) void k_transpose(const float* __restrict__ in,
                                                   unsigned short* __restrict__ out,
                                                   int R, int C)
{
  __shared__ unsigned short tile[64 * 68];
  const int tid = threadIdx.x;
  const long boff = (long)blockIdx.z * (long)R * (long)C;
  in += boff; out += boff;
  const int c0 = blockIdx.x * 64, r0 = blockIdx.y * 64;
  const int rr = tid >> 4;         // 0..15
  const int c4 = (tid & 15) * 4;   // 0..60
#pragma unroll
  for (int i = 0; i < 4; i++){
    int r = rr + i * 16;
    floatx4 v = *(const floatx4*)(in + (long)(r0 + r) * C + c0 + c4);
#pragma unroll
    for (int u = 0; u < 4; u++) tile[r * 68 + c4 + u] = f2bf(v[u]);
  }
  __syncthreads();
#pragma unroll
  for (int i = 0; i < 4; i++){
    int cc = rr + i * 16;
    short4v v;
#pragma unroll
    for (int u = 0; u < 4; u++) v[u] = (short)tile[(c4 + u) * 68 + cc];
    *(short4v*)(out + (long)(c0 + cc) * R + r0 + c4) = v;
  }
}

// -------- elementwise convert: bf16 copy of x ---------------------------------------------
__global__ __launch_bounds__(256) void k_xconv(const float* __restrict__ xf,
                                               unsigned short* __restrict__ xb)
{
  const long i = ((long)blockIdx.x * 256 + threadIdx.x) * 4;
  floatx4 v = *(const floatx4*)(xf + i);
  short4v o;
#pragma unroll
  for (int u = 0; u < 4; u++) o[u] = (short)f2bf(v[u]);
  *(short4v*)(xb + i) = o;
}

// -------- fold: W[d][h*24+e] = sum_dh head[d][h*128+dh]*choice[e][dh]  (fp64) -------------
__global__ __launch_bounds__(128) void k_fold(const float* __restrict__ head,
                                              const float* __restrict__ choice,
                                              double* __restrict__ W)
{
  __shared__ double hrow[768];
  const int d = blockIdx.x;
  for (int i = threadIdx.x; i < 768; i += 128) hrow[i] = (double)head[(long)d * 768 + i];
  __syncthreads();
  for (int c = threadIdx.x; c < 144; c += 128){
    int h = c / 24, e = c % 24;
    double a = 0.0;
    const double* hr = hrow + h * 128;
    const float* ch = choice + e * 128;
#pragma unroll 8
    for (int k = 0; k < 128; k++) a += hr[k] * (double)ch[k];
    W[(long)d * 144 + c] = a;
  }
}

// -------- gates: logits = x @ W (fp64), softmax over e per token --------------------------
// x: [8192][768] fp32 (rows = (b,s)); W: [768][144]; gatesT: [b*24+e][6144] fp64
__global__ __launch_bounds__(256) void k_gates(const float* __restrict__ xg,
                                               const double* __restrict__ W,
                                               double* __restrict__ gatesT)
{
  __shared__ double lds[6784];     // 54.3 KB: xs[2048] + Ws[4608]
  double* xs = lds;                // [32 k][64 rows]
  double* Ws = lds + 2048;         // [32 k][144]
  const int tid = threadIdx.x;
  const int tx = tid & 15;         // col group: cols c = tx + 16*j, j<9
  const int ty = tid >> 4;         // row group: rows r = ty*4 + i
  const int row0 = blockIdx.x * 64;

  double acc[4][9];
#pragma unroll
  for (int i = 0; i < 4; i++)
#pragma unroll
    for (int j = 0; j < 9; j++) acc[i][j] = 0.0;

  for (int k0 = 0; k0 < 768; k0 += 32){
    {
      int rr = tid >> 2;                // 0..63
      int kk8 = (tid & 3) * 8;          // 0,8,16,24
      const float* src = xg + (long)(row0 + rr) * 768 + k0 + kk8;
      floatx4 v0 = *(const floatx4*)src;
      floatx4 v1 = *(const floatx4*)(src + 4);
#pragma unroll
      for (int u = 0; u < 4; u++) xs[(kk8 + u) * 64 + rr] = (double)v0[u];
#pragma unroll
      for (int u = 0; u < 4; u++) xs[(kk8 + 4 + u) * 64 + rr] = (double)v1[u];
    }
    for (int f = tid; f < 4608; f += 256) Ws[f] = W[(long)k0 * 144 + f];
    __syncthreads();
    for (int kk = 0; kk < 32; kk++){
      double xv[4];
#pragma unroll
      for (int i = 0; i < 4; i++) xv[i] = xs[kk * 64 + ty * 4 + i];
#pragma unroll
      for (int j = 0; j < 9; j++){
        double wv = Ws[kk * 144 + tx + 16 * j];
#pragma unroll
        for (int i = 0; i < 4; i++) acc[i][j] += xv[i] * wv;
      }
    }
    __syncthreads();
  }

  // softmax in two 32-row phases (LDS reuse)
  double* gt = lds;  // [32][144]
  for (int phase = 0; phase < 2; ++phase){
    if ((ty >> 3) == phase){
      int rbase = (ty & 7) * 4;
#pragma unroll
      for (int i = 0; i < 4; i++)
#pragma unroll
        for (int j = 0; j < 9; j++) gt[(rbase + i) * 144 + tx + 16 * j] = acc[i][j];
    }
    __syncthreads();
    for (int g = tid; g < 192; g += 256){
      int r = g / 6, h = g % 6;
      const double* base = gt + r * 144 + h * 24;
      double m = base[0];
      for (int e = 1; e < 24; e++) m = fmax(m, base[e]);
      double s = 0.0;
      for (int e = 0; e < 24; e++) s += exp(base[e] - m);
      double is = 1.0 / s;
      int R = row0 + phase * 32 + r;
      int b = R >> 10, srow = R & 1023;
      int n = srow * 6 + h;
      for (int e = 0; e < 24; e++)
        gatesT[((long)(b * 24 + e)) * 6144 + n] = exp(base[e] - m) * is;
    }
    __syncthreads();
  }
}

// -------- top-K=1024 of 6144 per (b,e), exact fp64, jax tie semantics ---------------------
DEV int blk_reduce(int v, volatile int* sbuf, int tid){
#pragma unroll
  for (int off = 32; off > 0; off >>= 1) v += __shfl_down(v, off);
  __syncthreads();
  if ((tid & 63) == 0) sbuf[tid >> 6] = v;
  __syncthreads();
  return sbuf[0] + sbuf[1] + sbuf[2] + sbuf[3];
}

__global__ __launch_bounds__(256) void k_topk(const double* __restrict__ gatesT,
                                              int* __restrict__ Kidx, float* __restrict__ Gval,
                                              int* __restrict__ cnt, unsigned short* __restrict__ inv)
{
  __shared__ int sbuf[4];
  __shared__ int s_pos;
  const int tid = threadIdx.x;
  const int be = blockIdx.x;
  const int b = be / 24, e = be % 24;
  const double* g = gatesT + (long)be * 6144;

  unsigned long long key[24];
#pragma unroll
  for (int j = 0; j < 24; j++)
    key[j] = (unsigned long long)__double_as_longlong(g[tid + 256 * j]);

  // bisection on value-key: find T = 1024th largest (positive doubles: bit order = value order)
  unsigned long long lo = 0ull, hi = ~0ull;
  for (int it = 0; it < 64; ++it){
    if (hi - lo <= 1ull) break;
    unsigned long long mid = lo + ((hi - lo) >> 1);
    int c = 0;
#pragma unroll
    for (int j = 0; j < 24; j++) c += (key[j] > mid) ? 1 : 0;
    c = blk_reduce(c, sbuf, tid);
    if (c >= 1024) lo = mid; else hi = mid;
  }
  const unsigned long long T = hi;
  int cg = 0;
#pragma unroll
  for (int j = 0; j < 24; j++) cg += (key[j] > T) ? 1 : 0;
  cg = blk_reduce(cg, sbuf, tid);
  const int need = 1024 - cg;   // >= 1 by construction

  // bisection on index among ties (==T): smallest `need` indices win (jax top_k)
  int lo2 = 0, hi2 = 6144;
  for (int it = 0; it < 13; ++it){
    if (hi2 - lo2 <= 1) break;
    int mid = (lo2 + hi2) >> 1;
    int c = 0;
#pragma unroll
    for (int j = 0; j < 24; j++) c += (key[j] == T && (tid + 256 * j) < mid) ? 1 : 0;
    c = blk_reduce(c, sbuf, tid);
    if (c >= need) hi2 = mid; else lo2 = mid;
  }
  const int m = hi2;

  if (tid == 0) s_pos = 0;
  __syncthreads();
#pragma unroll
  for (int j = 0; j < 24; j++){
    int n = tid + 256 * j;
    bool sel = (key[j] > T) || (key[j] == T && n < m);
    if (sel){
      int slot = atomicAdd(&s_pos, 1);
      Kidx[(long)be * 1024 + slot] = n;
      Gval[(long)be * 1024 + slot] = (float)__longlong_as_double((long long)key[j]);
      int t = b * 6144 + n;
      int p = atomicAdd(&cnt[t], 1);
      inv[(long)t * 24 + p] = (unsigned short)(e * 1024 + slot);
    }
  }
}

// -------- bf16 MFMA GEMM (BT input), 128x128 tile, BK=64 ----------------------------------
// MODE 0: C[M,N] = A@B                (plain; OUTF=1 -> fp32 C)
// MODE 1: per chunk z=(b,ec): h = silu(gather(x1, Kidx) @ w1)
// MODE 2: per chunk z=(b,ec): Y = (h @ w2) * Gval[row]
template<int MODE, int OUTF>
__global__ __launch_bounds__(256, 2) void k_gemm(const unsigned short* __restrict__ Abase,
    const unsigned short* __restrict__ BTbase, unsigned short* __restrict__ Cbase,
    float* __restrict__ Cfbase,
    const int* __restrict__ KidxAll, const float* __restrict__ GvalAll,
    int M, int N, int K, int e0, int EC)
{
  __shared__ unsigned short As[128 * 64];
  __shared__ unsigned short Bs[128 * 64];
  const int tid = threadIdx.x;
  const int lane = tid & 63;
  const int w = tid >> 6;
  const int wy = w >> 1, wx = w & 1;
  const int m0 = blockIdx.x * 128;
  const int n0 = blockIdx.y * 128;

  const unsigned short* A = Abase;
  const unsigned short* BT = BTbase;
  unsigned short* C = Cbase;
  const int* idx = 0; const float* scl = 0;
  if (MODE == 1){
    const int z = blockIdx.z, b = z / EC, e = e0 + z % EC;
    A   = Abase + (long)b * 6144 * 128;
    BT  = BTbase + (long)e * 384 * 128;
    C   = Cbase + (long)z * 1024 * 384;
    idx = KidxAll + (long)(b * 24 + e) * 1024;
  } else if (MODE == 2){
    const int z = blockIdx.z, b = z / EC, e = e0 + z % EC;
    A   = Abase + (long)z * 1024 * 384;
    BT  = BTbase + (long)e * 128 * 384;
    C   = Cbase + (long)z * 1024 * 128;          // chunk-local Y
    scl = GvalAll + (long)(b * 24 + e) * 1024;
  }

  floatx4 acc[4][4];
  {
    floatx4 z4 = {0.f, 0.f, 0.f, 0.f};
#pragma unroll
    for (int i = 0; i < 4; i++)
#pragma unroll
      for (int j = 0; j < 4; j++) acc[i][j] = z4;
  }

  const int rsub = lane >> 3;          // 0..7
  const int kcol = (lane & 7) * 8;     // bf16 k-offset

  for (int k0 = 0; k0 < K; k0 += 64){
#pragma unroll
    for (int i = 0; i < 4; i++){
      const int inst = w * 4 + i;        // 0..15, each stages 8 rows x 64k (1KB)
      const int rr = inst * 8 + rsub;
      long arow = (MODE == 1) ? (long)idx[m0 + rr] : (long)(m0 + rr);
      gll16(A + arow * (long)K + k0 + kcol, &As[inst * 512], lane);
      gll16(BT + (long)(n0 + rr) * K + k0 + kcol, &Bs[inst * 512], lane);
    }
    __syncthreads();
#pragma unroll
    for (int ks = 0; ks < 2; ++ks){
      const int kb = ks * 32 + (lane >> 4) * 8;
      short8 af[4], bfr[4];
#pragma unroll
      for (int mi = 0; mi < 4; mi++) af[mi]  = *(const short8*)&As[(wy * 64 + mi * 16 + (lane & 15)) * 64 + kb];
#pragma unroll
      for (int ni = 0; ni < 4; ni++) bfr[ni] = *(const short8*)&Bs[(wx * 64 + ni * 16 + (lane & 15)) * 64 + kb];
#pragma unroll
      for (int mi = 0; mi < 4; mi++)
#pragma unroll
        for (int ni = 0; ni < 4; ni++)
          acc[mi][ni] = __builtin_amdgcn_mfma_f32_16x16x32_bf16(af[mi], bfr[ni], acc[mi][ni], 0, 0, 0);
    }
    __syncthreads();
  }

  const int ml = lane & 15;
  const int rq = (lane >> 4) * 4;
#pragma unroll
  for (int mi = 0; mi < 4; mi++){
    const int rowb = m0 + wy * 64 + mi * 16 + rq;
    float s4[4];
    if (MODE == 2){
#pragma unroll
      for (int r = 0; r < 4; r++) s4[r] = scl[rowb + r];
    }
#pragma unroll
    for (int ni = 0; ni < 4; ni++){
      const int col = n0 + wx * 64 + ni * 16 + ml;
#pragma unroll
      for (int r = 0; r < 4; r++){
        float v = acc[mi][ni][r];
        if (MODE == 1) v = v / (1.f + __expf(-v));   // silu
        if (MODE == 2) v *= s4[r];
        if (OUTF) Cfbase[(long)(rowb + r) * N + col] = v;
        else      C[(long)(rowb + r) * N + col] = f2bf(v);
      }
    }
  }
}

// -------- combine (chunk): xacc[t][:] += sum over picks with e in [e0,e0+EC) --------------
__global__ __launch_bounds__(256) void k_combine_acc(const int* __restrict__ cnt,
    const unsigned short* __restrict__ inv, const unsigned short* __restrict__ Y,
    float* __restrict__ xacc, int e0, int EC)
{
  const int t = blockIdx.x * 4 + (threadIdx.x >> 6);   // token id, < 49152
  const int lane = threadIdx.x & 63;
  const int b = t / 6144;
  const int c = cnt[t];
  float a0 = 0.f, a1 = 0.f;
  bool any = false;
  for (int p = 0; p < c; ++p){
    int code = inv[(long)t * 24 + p];
    int e = code >> 10, k = code & 1023;
    if (e >= e0 && e < e0 + EC){
      const unsigned short* y = Y + (((long)(b * EC + (e - e0)) * 1024 + k) << 7) + lane * 2;
      a0 += bf2f(y[0]); a1 += bf2f(y[1]);
      any = true;
    }
  }
  if (any){
    float* o = xacc + ((long)t << 7) + lane * 2;
    o[0] += a0; o[1] += a1;
  }
}

// -------- convert fp32 accumulator -> bf16 token matrix -----------------------------------
__global__ __launch_bounds__(256) void k_convert(const float* __restrict__ xa,
                                                 unsigned short* __restrict__ xo)
{
  const long i = ((long)blockIdx.x * 256 + threadIdx.x) * 4;
  floatx4 v = *(const floatx4*)(xa + i);
  short4v o;
#pragma unroll
  for (int u = 0; u < 4; u++) o[u] = (short)f2bf(v[u]);
  *(short4v*)(xo + i) = o;
}

// ==========================================================================================
extern "C" void kernel_launch(void* const* d_in, const int* in_sizes, int n_in,
                              void* d_out, int out_size, void* d_ws, size_t ws_size,
                              hipStream_t stream)
{
  const float* x      = (const float*)d_in[0];
  const float* choice = (const float*)d_in[1];
  const float* w1     = (const float*)d_in[2];
  const float* w2     = (const float*)d_in[3];
  const float* head   = (const float*)d_in[4];
  const float* merge  = (const float*)d_in[5];
  float* out = (float*)d_out;
  (void)in_sizes; (void)n_in; (void)out_size;

  char* p = (char*)d_ws;
  auto alloc = [&p](size_t bytes) -> void* {
    void* q = (void*)p; p += (bytes + 255) & ~(size_t)255; return q;
  };

  // ---- fixed small buffers (~12.1 MB) ----
  unsigned short* headT = (unsigned short*)alloc((size_t)768 * 768 * 2);
  unsigned short* mergeT= (unsigned short*)alloc((size_t)768 * 768 * 2);
  unsigned short* w1T   = (unsigned short*)alloc((size_t)24 * 384 * 128 * 2);
  unsigned short* w2T   = (unsigned short*)alloc((size_t)24 * 128 * 384 * 2);
  double* W64           = (double*)alloc((size_t)768 * 144 * 8);
  int* Kidx             = (int*)alloc((size_t)192 * 1024 * 4);
  float* Gval           = (float*)alloc((size_t)192 * 1024 * 4);
  int* cnt              = (int*)alloc((size_t)49152 * 4);
  unsigned short* inv   = (unsigned short*)alloc((size_t)49152 * 24 * 2);
  // ---- big buffers with aliasing ----
  unsigned short* xb    = (unsigned short*)alloc((size_t)8192 * 768 * 2);   // 12.58 MB
  double* gatesT        = (double*)xb;   // 9.44 MB; live only after xb's last use (x1 GEMM)
  unsigned short* xout  = xb;            // live only after gatesT dead (post-topk chunks)
  unsigned short* x1    = (unsigned short*)alloc((size_t)8192 * 768 * 2);   // 12.58 MB
  float* xacc           = out;           // fp32 combine accumulator lives in d_out (25.17 MB)

  // ---- adaptive expert-chunk size: per-EC cost = h (6.29 MB) + Y (2.10 MB) ----
  size_t used = (size_t)(p - (char*)d_ws);
  size_t remain = (ws_size > used) ? (ws_size - used) : 0;
  const size_t perEC = (size_t)8 * 1024 * (384 + 128) * 2 + 512;   // 8.39 MB
  int EC = 1;
  const int opts[8] = {24, 12, 8, 6, 4, 3, 2, 1};
  for (int i = 0; i < 8; i++){ if ((size_t)opts[i] * perEC <= remain){ EC = opts[i]; break; } }
  unsigned short* hbuf = (unsigned short*)alloc((size_t)EC * 8 * 1024 * 384 * 2);
  unsigned short* Ybuf = (unsigned short*)alloc((size_t)EC * 8 * 1024 * 128 * 2);

  hipMemsetAsync(cnt, 0, (size_t)49152 * 4, stream);
  k_transpose<<<dim3(12, 12, 1), 256, 0, stream>>>(head, headT, 768, 768);
  k_transpose<<<dim3(12, 12, 1), 256, 0, stream>>>(merge, mergeT, 768, 768);
  k_transpose<<<dim3(6, 2, 24), 256, 0, stream>>>(w1, w1T, 128, 384);
  k_transpose<<<dim3(2, 6, 24), 256, 0, stream>>>(w2, w2T, 384, 128);
  k_fold<<<dim3(768), 128, 0, stream>>>(head, choice, W64);
  k_xconv<<<dim3(6144), 256, 0, stream>>>(x, xb);
  k_gemm<0,0><<<dim3(64, 6, 1), 256, 0, stream>>>(xb, headT, x1, nullptr, nullptr, nullptr, 8192, 768, 768, 0, 1);
  // xb dead; gatesT (aliases xb) live from here
  k_gates<<<dim3(128), 256, 0, stream>>>(x, W64, gatesT);
  k_topk<<<dim3(192), 256, 0, stream>>>(gatesT, Kidx, Gval, cnt, inv);
  // gatesT dead; xacc lives in d_out
  hipMemsetAsync(xacc, 0, (size_t)8192 * 768 * 4, stream);
  for (int e0 = 0; e0 < 24; e0 += EC){
    k_gemm<1,0><<<dim3(8, 3, 8 * EC), 256, 0, stream>>>(x1, w1T, hbuf, nullptr, Kidx, Gval, 1024, 384, 128, e0, EC);
    k_gemm<2,0><<<dim3(8, 1, 8 * EC), 256, 0, stream>>>(hbuf, w2T, Ybuf, nullptr, Kidx, Gval, 1024, 128, 384, e0, EC);
    k_combine_acc<<<dim3(12288), 256, 0, stream>>>(cnt, inv, Ybuf, xacc, e0, EC);
  }
  k_convert<<<dim3(6144), 256, 0, stream>>>(xacc, xout);   // d_out -> bf16 xout (ws)
  k_gemm<0,1><<<dim3(64, 6, 1), 256, 0, stream>>>(xout, mergeT, nullptr, out, nullptr, nullptr, 8192, 768, 768, 0, 1);
}